// Round 9
// baseline (431.573 us; speedup 1.0000x reference)
//
#include <hip/hip_runtime.h>
#include <stdint.h>

// ---------------------------------------------------------------------------
// MultiGraph hetero-GNN + gumbel-top-k edge pruning, fp32 throughout.
// Round 9: fused_layer v2 — 16 nodes/block (2x W reuse), flat-contiguous LDS
// W staging (kills r8's 16-way store conflicts), P-stage staged through LDS
// in k-chunks (kills ~1.5GB redundant WP reads). Per-output fp chains
// (agg slot-ascending; GEMM part-major k-ascending; P k-ascending) preserved
// -> bit-exact vs r7/r8. LDS = 40KB -> 4 blocks/CU.
// PRNG: JAX threefry2x32, partitionable path (verified absmax=0.0 r1-r8).
// ---------------------------------------------------------------------------

namespace {

constexpr int NPn = 4096;
constexpr int NAn = 2048;
constexpr int Hh  = 128;
constexpr int EPPc = 131072;
constexpr int EAAc = 65536;
constexpr int KSEL = 5;
constexpr int BSLOT = 128;   // bucket capacity per node (deg<128: Poisson-32, e^-85 tail)

// bucket segments (cnt index = co + node; entries base = (co+node)*128):
// 0: pp-dst (4096)   4096: aa-dst (2048)   6144: pa-dst (2048)
// 8192: ap-dst (4096) 12288: pp-src (4096) 16384: aa-src (2048)
// payloads: pp: (other<<18)|e  aa: (other<<16)|e  pa/ap: src only

__host__ __device__ static inline void tf2x32(uint32_t k0, uint32_t k1,
                                              uint32_t& x0, uint32_t& x1) {
  uint32_t ks2 = k0 ^ k1 ^ 0x1BD11BDAu;
  x0 += k0; x1 += k1;
#define TF_R(r) { x0 += x1; x1 = (x1 << (r)) | (x1 >> (32 - (r))); x1 ^= x0; }
  TF_R(13) TF_R(15) TF_R(26) TF_R(6)
  x0 += k1;  x1 += ks2 + 1u;
  TF_R(17) TF_R(29) TF_R(16) TF_R(24)
  x0 += ks2; x1 += k0 + 2u;
  TF_R(13) TF_R(15) TF_R(26) TF_R(6)
  x0 += k0;  x1 += k1 + 3u;
  TF_R(17) TF_R(29) TF_R(16) TF_R(24)
  x0 += k1;  x1 += ks2 + 4u;
  TF_R(13) TF_R(15) TF_R(26) TF_R(6)
  x0 += ks2; x1 += k0 + 5u;
#undef TF_R
}

// ---------------- bucket scatter (r7 verbatim) ----------------
__global__ __launch_bounds__(256) void scatter_kernel(
    const int* src_pp, const int* dst_pp, const int* src_aa, const int* dst_aa,
    const int* src_pa, const int* dst_pa, const int* src_ap, const int* dst_ap,
    int* cnt, int* entries)
{
  int i = blockIdx.x * 256 + threadIdx.x;
  int key, pl;
  if (i < 131072) {                       // pp by dst
    int e = i;
    key = 0 + dst_pp[e]; pl = (src_pp[e] << 18) | e;
  } else if (i < 196608) {                // aa by dst
    int e = i - 131072;
    key = 4096 + dst_aa[e]; pl = (src_aa[e] << 16) | e;
  } else if (i < 327680) {                // pa by dst (payload = src paper)
    int e = i - 196608;
    key = 6144 + dst_pa[e]; pl = src_pa[e];
  } else if (i < 458752) {                // ap by dst (payload = src author)
    int e = i - 327680;
    key = 8192 + dst_ap[e]; pl = src_ap[e];
  } else if (i < 589824) {                // pp by src (payload = (dst<<18)|e)
    int e = i - 458752;
    key = 12288 + src_pp[e]; pl = (dst_pp[e] << 18) | e;
  } else if (i < 655360) {                // aa by src
    int e = i - 589824;
    key = 16384 + src_aa[e]; pl = (dst_aa[e] << 16) | e;
  } else return;
  int pos = atomicAdd(&cnt[key], 1);
  if (pos < BSLOT) entries[key * BSLOT + pos] = pl;
}

// ---------------- fused agg + GEMM (+ optional P projections), v2 ----------------------
// 16 nodes/block. Agg: half-wave per node, 2 reps (r7 body). GEMM: C[16][128] =
// X@W0 + M@W1 (+Z@W2), W staged via flat-contiguous 16KB Wst chunks; per-output
// chain part-major k-ascending (identical to r7 gemm_b). P: two 128x256 halves,
// staged via Wst in 8 k-chunks each, k ascending (identical to r7 gemmP).
struct FDesc {
  const float* gsrc; const float* wArr; int cntOff; int shift;
  float* Mout;                                  // agg-only output (when W0 == null)
  const float* Aself; const float* W0; const float* W1;
  const float* A2;  const float* W2;            // optional part 2
  float* C; int relu;                           // C may be null (P-only)
  const float* WP; float* P1; float* P2;        // optional P stage
};
struct FArgs { FDesc d[4]; int bstart[5]; int nd; };

__global__ __launch_bounds__(256) void fused_layer(FArgs fa, const int* __restrict__ cnt,
                                                   const int* __restrict__ entries)
{
  __shared__ __align__(16) float Ms[16 * 128];
  __shared__ __align__(16) float Xs[16 * 128];
  __shared__ __align__(16) float Zs[16 * 128];
  __shared__ __align__(16) float Wst[4096];     // 16KB flat staging
  int blk = blockIdx.x, tid = threadIdx.x;
  int di = 0;
  while (di < fa.nd - 1 && blk >= fa.bstart[di + 1]) ++di;
  FDesc D = fa.d[di];
  int node0 = (blk - fa.bstart[di]) * 16;
  // ---- agg phase (r7 body; half-wave per node, 2 nodes sequentially) ----
  {
    int hw = tid >> 5;
    int fl = (tid & 31) << 2;
    for (int rep = 0; rep < 2; ++rep) {
      int nloc = hw + rep * 8;
      int node = node0 + nloc;
      int deg = cnt[D.cntOff + node];
      const int* ent = entries + (size_t)(D.cntOff + node) * BSLOT;
      const float* h = D.gsrc;
      int sh = D.shift;
      float ax = 0.f, ay = 0.f, az = 0.f, aw = 0.f;
      if (D.wArr) {
        unsigned mask = (1u << sh) - 1u;
        int k = 0;
        for (; k + 3 < deg; k += 4) {
          unsigned p0 = (unsigned)ent[k], p1 = (unsigned)ent[k + 1];
          unsigned p2 = (unsigned)ent[k + 2], p3 = (unsigned)ent[k + 3];
          float w0 = D.wArr[p0 & mask], w1 = D.wArr[p1 & mask];
          float w2v = D.wArr[p2 & mask], w3 = D.wArr[p3 & mask];
          float4 v0, v1, v2, v3;
          if (w0 != 0.f) v0 = *(const float4*)&h[(size_t)(p0 >> sh) * Hh + fl];
          if (w1 != 0.f) v1 = *(const float4*)&h[(size_t)(p1 >> sh) * Hh + fl];
          if (w2v != 0.f) v2 = *(const float4*)&h[(size_t)(p2 >> sh) * Hh + fl];
          if (w3 != 0.f) v3 = *(const float4*)&h[(size_t)(p3 >> sh) * Hh + fl];
          if (w0 != 0.f) { ax += v0.x; ay += v0.y; az += v0.z; aw += v0.w; }
          if (w1 != 0.f) { ax += v1.x; ay += v1.y; az += v1.z; aw += v1.w; }
          if (w2v != 0.f) { ax += v2.x; ay += v2.y; az += v2.z; aw += v2.w; }
          if (w3 != 0.f) { ax += v3.x; ay += v3.y; az += v3.z; aw += v3.w; }
        }
        for (; k < deg; ++k) {
          unsigned pl = (unsigned)ent[k];
          float wt = D.wArr[pl & mask];
          if (wt != 0.f) {
            float4 v = *(const float4*)&h[(size_t)(pl >> sh) * Hh + fl];
            ax += v.x; ay += v.y; az += v.z; aw += v.w;
          }
        }
      } else {
        int k = 0;
        for (; k + 7 < deg; k += 8) {
          unsigned p0 = (unsigned)ent[k],     p1 = (unsigned)ent[k + 1];
          unsigned p2 = (unsigned)ent[k + 2], p3 = (unsigned)ent[k + 3];
          unsigned p4 = (unsigned)ent[k + 4], p5 = (unsigned)ent[k + 5];
          unsigned p6 = (unsigned)ent[k + 6], p7 = (unsigned)ent[k + 7];
          float4 v0 = *(const float4*)&h[(size_t)(p0 >> sh) * Hh + fl];
          float4 v1 = *(const float4*)&h[(size_t)(p1 >> sh) * Hh + fl];
          float4 v2 = *(const float4*)&h[(size_t)(p2 >> sh) * Hh + fl];
          float4 v3 = *(const float4*)&h[(size_t)(p3 >> sh) * Hh + fl];
          float4 v4 = *(const float4*)&h[(size_t)(p4 >> sh) * Hh + fl];
          float4 v5 = *(const float4*)&h[(size_t)(p5 >> sh) * Hh + fl];
          float4 v6 = *(const float4*)&h[(size_t)(p6 >> sh) * Hh + fl];
          float4 v7 = *(const float4*)&h[(size_t)(p7 >> sh) * Hh + fl];
          ax += v0.x; ay += v0.y; az += v0.z; aw += v0.w;
          ax += v1.x; ay += v1.y; az += v1.z; aw += v1.w;
          ax += v2.x; ay += v2.y; az += v2.z; aw += v2.w;
          ax += v3.x; ay += v3.y; az += v3.z; aw += v3.w;
          ax += v4.x; ay += v4.y; az += v4.z; aw += v4.w;
          ax += v5.x; ay += v5.y; az += v5.z; aw += v5.w;
          ax += v6.x; ay += v6.y; az += v6.z; aw += v6.w;
          ax += v7.x; ay += v7.y; az += v7.z; aw += v7.w;
        }
        for (; k < deg; ++k) {
          unsigned pl = (unsigned)ent[k];
          float4 v = *(const float4*)&h[(size_t)(pl >> sh) * Hh + fl];
          ax += v.x; ay += v.y; az += v.z; aw += v.w;
        }
      }
      float cd = fmaxf((float)deg, 1.0f);
      float4 o; o.x = ax / cd; o.y = ay / cd; o.z = az / cd; o.w = aw / cd;
      if (D.W0 == nullptr) {
        *(float4*)&D.Mout[(size_t)node * Hh + fl] = o;
      } else {
        *(float4*)&Ms[nloc * 128 + fl] = o;
      }
    }
  }
  if (D.W0 == nullptr) return;   // agg-only segment (uniform per block)
  // ---- stage self rows (and part-2 rows): contiguous, coalesced ----
  {
    int rm = tid >> 4;            // 16 rows, 16 threads/row
    int cq = (tid & 15) << 3;     // 8 floats/thread
    *(float4*)&Xs[rm * 128 + cq]     = *(const float4*)&D.Aself[(size_t)(node0 + rm) * 128 + cq];
    *(float4*)&Xs[rm * 128 + cq + 4] = *(const float4*)&D.Aself[(size_t)(node0 + rm) * 128 + cq + 4];
    if (D.A2) {
      *(float4*)&Zs[rm * 128 + cq]     = *(const float4*)&D.A2[(size_t)(node0 + rm) * 128 + cq];
      *(float4*)&Zs[rm * 128 + cq + 4] = *(const float4*)&D.A2[(size_t)(node0 + rm) * 128 + cq + 4];
    }
  }
  // ---- GEMM: thread owns (m = tid>>4, cols colq*8..+7); part-major, k ascending ----
  int m = tid >> 4, colq = tid & 15;
  float4 acc0 = {0.f, 0.f, 0.f, 0.f}, acc1 = {0.f, 0.f, 0.f, 0.f};
  int parts = D.A2 ? 3 : 2;
  for (int p = 0; p < parts; ++p) {
    const float* W = (p == 0) ? D.W0 : (p == 1) ? D.W1 : D.W2;
    const float* AR = (p == 0) ? Xs : (p == 1) ? Ms : Zs;
    for (int c = 0; c < 4; ++c) {
      __syncthreads();             // prev chunk consumed / agg+stage visible
#pragma unroll
      for (int jj = 0; jj < 4; ++jj) {
        // flat-contiguous store: word jj*1024 + tid*4 -> conflict-free
        *(float4*)&Wst[jj * 1024 + tid * 4] =
            *(const float4*)&W[(size_t)(c * 32 + jj * 8 + (tid >> 5)) * 128 + ((tid & 31) << 2)];
      }
      __syncthreads();
#pragma unroll
      for (int k = 0; k < 32; ++k) {
        float a = AR[m * 128 + c * 32 + k];
        float4 w0 = *(const float4*)&Wst[k * 128 + colq * 8];
        float4 w1 = *(const float4*)&Wst[k * 128 + colq * 8 + 4];
        acc0.x += a * w0.x; acc0.y += a * w0.y; acc0.z += a * w0.z; acc0.w += a * w0.w;
        acc1.x += a * w1.x; acc1.y += a * w1.y; acc1.z += a * w1.z; acc1.w += a * w1.w;
      }
    }
  }
  if (D.relu) {
    acc0.x = fmaxf(acc0.x, 0.f); acc0.y = fmaxf(acc0.y, 0.f);
    acc0.z = fmaxf(acc0.z, 0.f); acc0.w = fmaxf(acc0.w, 0.f);
    acc1.x = fmaxf(acc1.x, 0.f); acc1.y = fmaxf(acc1.y, 0.f);
    acc1.z = fmaxf(acc1.z, 0.f); acc1.w = fmaxf(acc1.w, 0.f);
  }
  if (D.C) {
    *(float4*)&D.C[(size_t)(node0 + m) * 128 + colq * 8]     = acc0;
    *(float4*)&D.C[(size_t)(node0 + m) * 128 + colq * 8 + 4] = acc1;
  }
  if (D.WP == nullptr) return;
  // ---- P stage: h rows -> Xs (reuse), then P1/P2 = h @ WP halves (staged) ----
  __syncthreads();
  *(float4*)&Xs[m * 128 + colq * 8]     = acc0;
  *(float4*)&Xs[m * 128 + colq * 8 + 4] = acc1;
  for (int half = 0; half < 2; ++half) {
    float4 pA = {0,0,0,0}, pB = {0,0,0,0}, pC = {0,0,0,0}, pD = {0,0,0,0};
    for (int kc = 0; kc < 8; ++kc) {
      __syncthreads();             // prev chunk consumed / Xs store visible
#pragma unroll
      for (int jj = 0; jj < 4; ++jj) {
        // Wst16 view [16][256]: word jj*1024 + tid*4 -> k = jj*4+(tid>>6), col = (tid&63)*4
        *(float4*)&Wst[jj * 1024 + tid * 4] =
            *(const float4*)&D.WP[(size_t)(half * 128 + kc * 16 + jj * 4 + (tid >> 6)) * 256 +
                                  ((tid & 63) << 2)];
      }
      __syncthreads();
#pragma unroll
      for (int k = 0; k < 16; ++k) {
        float a = Xs[m * 128 + kc * 16 + k];
        int base = k * 256 + colq * 16;
        float4 w0 = *(const float4*)&Wst[base];
        float4 w1 = *(const float4*)&Wst[base + 4];
        float4 w2 = *(const float4*)&Wst[base + 8];
        float4 w3 = *(const float4*)&Wst[base + 12];
        pA.x += a * w0.x; pA.y += a * w0.y; pA.z += a * w0.z; pA.w += a * w0.w;
        pB.x += a * w1.x; pB.y += a * w1.y; pB.z += a * w1.z; pB.w += a * w1.w;
        pC.x += a * w2.x; pC.y += a * w2.y; pC.z += a * w2.z; pC.w += a * w2.w;
        pD.x += a * w3.x; pD.y += a * w3.y; pD.z += a * w3.z; pD.w += a * w3.w;
      }
    }
    float* PD = half ? D.P2 : D.P1;
    size_t ob = (size_t)(node0 + m) * 256 + colq * 16;
    *(float4*)&PD[ob]      = pA;
    *(float4*)&PD[ob + 4]  = pB;
    *(float4*)&PD[ob + 8]  = pC;
    *(float4*)&PD[ob + 12] = pD;
  }
}

// ---------------- fused edge-MLP + sparse coalesce + masked gumbel top-5 (r7 verbatim) --
__global__ __launch_bounds__(256) void row_topk(
    const float* __restrict__ P1pp, const float* __restrict__ P2pp,
    const float* __restrict__ b1pp, const float* __restrict__ W2pp,
    const float* __restrict__ b2pp,
    const float* __restrict__ P1aa, const float* __restrict__ P2aa,
    const float* __restrict__ b1aa, const float* __restrict__ W2aa,
    const float* __restrict__ b2aa,
    const int* __restrict__ cnt, const int* __restrict__ entries,
    float* __restrict__ w_pp, float* __restrict__ w_aa,
    uint32_t kpp0, uint32_t kpp1, uint32_t kaa0, uint32_t kaa1)
{
  __shared__ float P1s[256], b1s[256], w2s[256];
  __shared__ int   dS[128];
  __shared__ float pS[128];
  __shared__ int   sel5[KSEL];
  int blk = blockIdx.x, tid = threadIdx.x;
  int lane = tid & 63, wv = tid >> 6;
  int row, Ncols, shift, co; unsigned mask;
  const float* P1; const float* P2; const float* b1; const float* W2; const float* b2;
  float* wout; uint32_t k0, k1;
  if (blk < NPn) {
    row = blk; Ncols = NPn; shift = 18; mask = 0x3FFFFu; co = 12288;
    P1 = P1pp; P2 = P2pp; b1 = b1pp; W2 = W2pp; b2 = b2pp;
    wout = w_pp; k0 = kpp0; k1 = kpp1;
  } else {
    row = blk - NPn; Ncols = NAn; shift = 16; mask = 0xFFFFu; co = 16384;
    P1 = P1aa; P2 = P2aa; b1 = b1aa; W2 = W2aa; b2 = b2aa;
    wout = w_aa; k0 = kaa0; k1 = kaa1;
  }
  const int* ent = entries + (size_t)(co + row) * BSLOT;
  int deg = cnt[co + row];
  P1s[tid] = P1[(size_t)row * 256 + tid];
  b1s[tid] = b1[tid];
  w2s[tid] = W2[tid * 2];
  __syncthreads();
  float bias2 = b2[0];
  int j = lane << 2;
  for (int k = wv * 4; k < deg; k += 16) {
    int n = deg - k; if (n > 4) n = 4;
    unsigned pl0 = (unsigned)ent[k];
    unsigned pl1 = (n > 1) ? (unsigned)ent[k + 1] : pl0;
    unsigned pl2 = (n > 2) ? (unsigned)ent[k + 2] : pl0;
    unsigned pl3 = (n > 3) ? (unsigned)ent[k + 3] : pl0;
    int d0 = (int)(pl0 >> shift), d1 = (int)(pl1 >> shift);
    int d2 = (int)(pl2 >> shift), d3 = (int)(pl3 >> shift);
    float4 q0 = *(const float4*)&P2[(size_t)d0 * 256 + j];
    float4 q1 = *(const float4*)&P2[(size_t)d1 * 256 + j];
    float4 q2 = *(const float4*)&P2[(size_t)d2 * 256 + j];
    float4 q3 = *(const float4*)&P2[(size_t)d3 * 256 + j];
    float pa = P1s[j + 0], pb = P1s[j + 1], pc = P1s[j + 2], pd = P1s[j + 3];
    float ba = b1s[j + 0], bb = b1s[j + 1], bc_ = b1s[j + 2], bd = b1s[j + 3];
    float wa = w2s[j + 0], wb = w2s[j + 1], wc = w2s[j + 2], wd = w2s[j + 3];
    float s0 = fmaxf(pa + q0.x + ba, 0.f) * wa + fmaxf(pb + q0.y + bb, 0.f) * wb +
               fmaxf(pc + q0.z + bc_, 0.f) * wc + fmaxf(pd + q0.w + bd, 0.f) * wd;
    float s1 = fmaxf(pa + q1.x + ba, 0.f) * wa + fmaxf(pb + q1.y + bb, 0.f) * wb +
               fmaxf(pc + q1.z + bc_, 0.f) * wc + fmaxf(pd + q1.w + bd, 0.f) * wd;
    float s2 = fmaxf(pa + q2.x + ba, 0.f) * wa + fmaxf(pb + q2.y + bb, 0.f) * wb +
               fmaxf(pc + q2.z + bc_, 0.f) * wc + fmaxf(pd + q2.w + bd, 0.f) * wd;
    float s3 = fmaxf(pa + q3.x + ba, 0.f) * wa + fmaxf(pb + q3.y + bb, 0.f) * wb +
               fmaxf(pc + q3.z + bc_, 0.f) * wc + fmaxf(pd + q3.w + bd, 0.f) * wd;
    for (int off = 32; off; off >>= 1) {
      s0 += __shfl_down(s0, off);
      s1 += __shfl_down(s1, off);
      s2 += __shfl_down(s2, off);
      s3 += __shfl_down(s3, off);
    }
    if (lane == 0) {
      dS[k] = d0; pS[k] = s0 + bias2;
      if (n > 1) { dS[k + 1] = d1; pS[k + 1] = s1 + bias2; }
      if (n > 2) { dS[k + 2] = d2; pS[k + 2] = s2 + bias2; }
      if (n > 3) { dS[k + 3] = d3; pS[k + 3] = s3 + bias2; }
    }
  }
  __syncthreads();
  if (deg > 0 && wv == 0) {
    int   e0 = (lane < deg) ? dS[lane] : -1;
    float q0v = (lane < deg) ? pS[lane] : 0.f;
    bool  two = (deg > 64);
    int   e1 = -1; float q1v = 0.f;
    if (two && 64 + lane < deg) { e1 = dS[64 + lane]; q1v = pS[64 + lane]; }
    float a0 = 0.f, a1 = 0.f;
    bool lead0 = (e0 >= 0), lead1 = (e1 >= 0);
    for (int j2 = 0; j2 < deg; ++j2) {
      int bj; float bp;
      if (j2 < 64) { bj = __shfl(e0, j2); bp = __shfl(q0v, j2); }
      else         { bj = __shfl(e1, j2 - 64); bp = __shfl(q1v, j2 - 64); }
      if (e0 >= 0 && bj == e0) { a0 += bp; if (j2 < lane) lead0 = false; }
      if (e1 >= 0 && bj == e1) { a1 += bp; if (j2 < 64 + lane) lead1 = false; }
    }
    uint32_t rowbase = (uint32_t)row * (uint32_t)Ncols;
    float y0 = -1e9f, y1 = -1e9f;
    bool c0 = lead0 && (a0 > 0.f);
    if (c0) {
      uint32_t x0 = 0u, x1 = rowbase + (uint32_t)e0;
      tf2x32(k0, k1, x0, x1);
      uint32_t bits = x0 ^ x1;
      float fv = __uint_as_float((bits >> 9) | 0x3f800000u) - 1.0f;
      float u = fmaxf(1e-10f, fv + 1e-10f);
      y0 = a0 + (-logf(-logf(u)));
    }
    bool c1 = lead1 && (a1 > 0.f);
    if (c1) {
      uint32_t x0 = 0u, x1 = rowbase + (uint32_t)e1;
      tf2x32(k0, k1, x0, x1);
      uint32_t bits = x0 ^ x1;
      float fv = __uint_as_float((bits >> 9) | 0x3f800000u) - 1.0f;
      float u = fmaxf(1e-10f, fv + 1e-10f);
      y1 = a1 + (-logf(-logf(u)));
    }
    int cnt2 = __popcll(__ballot(c0)) + __popcll(__ballot(c1));
    int nsel = cnt2 < KSEL ? cnt2 : KSEL;
    for (int it = 0; it < nsel; ++it) {
      float best; int bc;
      if (y1 > y0 || (y1 == y0 && (unsigned)e1 < (unsigned)e0)) { best = y1; bc = e1; }
      else { best = y0; bc = e0; }
      for (int mm = 32; mm; mm >>= 1) {
        float ov = __shfl_xor(best, mm); int oc = __shfl_xor(bc, mm);
        if (ov > best || (ov == best && (unsigned)oc < (unsigned)bc)) { best = ov; bc = oc; }
      }
      if (lane == 0) sel5[it] = bc;
      if (e0 == bc) y0 = -3.0e38f;
      if (e1 == bc) y1 = -3.0e38f;
    }
    if (nsel < KSEL && lane == 0) {
      int c = 0;
      for (int it = nsel; it < KSEL; ++it) {
        for (;;) {
          bool used = false;
          for (int q = 0; q < it; ++q) used |= (sel5[q] == c);
          if (!used) break;
          ++c;
        }
        sel5[it] = c++;
      }
    }
  }
  __syncthreads();
  for (int k = tid; k < deg; k += 256) {
    unsigned pl = (unsigned)ent[k];
    int d = (int)(pl >> shift);
    int e = (int)(pl & mask);
    float v = 0.f;
#pragma unroll
    for (int q = 0; q < KSEL; ++q) v = (sel5[q] == d) ? 1.f : v;
    wout[e] = v;
  }
}

// ---------------- fused GNN2-layer1 (single row) + classifier (r7 verbatim) -------------
__global__ __launch_bounds__(128) void final_kernel(
    const float* __restrict__ hp, const float* __restrict__ ha,
    const int* __restrict__ idxPtr, const float* __restrict__ wpp,
    const int* __restrict__ cnt, const int* __restrict__ entries,
    const float* __restrict__ Wself, const float* __restrict__ Wpp,
    const float* __restrict__ Wap,
    const float* __restrict__ Wc, const float* __restrict__ bc,
    float* __restrict__ out)
{
  __shared__ float selfr[128], mpp[128], mapr[128], t[128];
  int tid = threadIdx.x;
  int idx = idxPtr[0];
  selfr[tid] = hp[(size_t)idx * 128 + tid];
  {
    int deg = cnt[idx];                                   // pp-dst bucket
    const int* ent = entries + (size_t)idx * BSLOT;
    float acc = 0.f;
    for (int k = 0; k < deg; ++k) {
      unsigned pl = (unsigned)ent[k];
      int s = (int)(pl >> 18);
      int e = (int)(pl & 0x3FFFFu);
      acc += wpp[e] * hp[(size_t)s * 128 + tid];
    }
    mpp[tid] = acc / fmaxf((float)deg, 1.0f);
  }
  {
    int deg = cnt[8192 + idx];                            // ap-dst bucket
    const int* ent = entries + (size_t)(8192 + idx) * BSLOT;
    float acc = 0.f;
    for (int k = 0; k < deg; ++k) {
      int s = ent[k];
      acc += ha[(size_t)s * 128 + tid];
    }
    mapr[tid] = acc / fmaxf((float)deg, 1.0f);
  }
  __syncthreads();
  float s = 0.f;
  for (int m = 0; m < 128; ++m) {
    s += selfr[m] * Wself[m * 128 + tid] + mpp[m] * Wpp[m * 128 + tid] +
         mapr[m] * Wap[m * 128 + tid];
  }
  t[tid] = fmaxf(s, 0.f);
  __syncthreads();
  if (tid < 5) {
    float y = bc[tid];
    for (int k = 0; k < 128; ++k) y += t[k] * Wc[k * 5 + tid];
    out[tid] = y;
  }
}

}  // namespace

extern "C" void kernel_launch(void* const* d_in, const int* in_sizes, int n_in,
                              void* d_out, int out_size, void* d_ws, size_t ws_size,
                              hipStream_t stream)
{
  (void)in_sizes; (void)n_in; (void)out_size; (void)ws_size;
  const float* x_p = (const float*)d_in[0];
  const float* x_a = (const float*)d_in[1];
  const int* ei_pp = (const int*)d_in[2];
  const int* ei_aa = (const int*)d_in[3];
  const int* ei_pa = (const int*)d_in[4];
  const int* ei_ap = (const int*)d_in[5];
  const int* idxPtr = (const int*)d_in[8];
  const float* Wself_p0 = (const float*)d_in[9];
  const float* Wself_p1 = (const float*)d_in[10];
  const float* Wself_a0 = (const float*)d_in[11];
  const float* Wself_a1 = (const float*)d_in[12];
  const float* Wpp0 = (const float*)d_in[13]; const float* Wpp1 = (const float*)d_in[14];
  const float* Waa0 = (const float*)d_in[15]; const float* Waa1 = (const float*)d_in[16];
  const float* Wpa0 = (const float*)d_in[17]; /* Wpa1 unused: author L1 dropped */
  const float* Wap0 = (const float*)d_in[19]; const float* Wap1 = (const float*)d_in[20];
  const float* Wep1_pp = (const float*)d_in[21]; const float* bep1_pp = (const float*)d_in[22];
  const float* Wep2_pp = (const float*)d_in[23]; const float* bep2_pp = (const float*)d_in[24];
  const float* Wep1_aa = (const float*)d_in[25]; const float* bep1_aa = (const float*)d_in[26];
  const float* Wep2_aa = (const float*)d_in[27]; const float* bep2_aa = (const float*)d_in[28];
  const float* Wc = (const float*)d_in[29]; const float* bc = (const float*)d_in[30];

  float* out = (float*)d_out;
  float* w_pp_out = out + 5;
  float* w_aa_out = out + 5 + EPPc;

  const int* src_pp = ei_pp;  const int* dst_pp = ei_pp + EPPc;
  const int* src_aa = ei_aa;  const int* dst_aa = ei_aa + EAAc;
  const int* src_pa = ei_pa;  const int* dst_pa = ei_pa + 131072;
  const int* src_ap = ei_ap;  const int* dst_ap = ei_ap + 131072;

  // ---- workspace layout (bump allocator; cnt first: it gets memset) ----
  char* p = (char*)d_ws;
  auto alloc = [&](size_t bytes) -> void* {
    void* r = (void*)p;
    p += (bytes + 255) & ~(size_t)255;
    return r;
  };
  int* cnt     = (int*)alloc(18432 * sizeof(int));
  int* entries = (int*)alloc((size_t)18432 * BSLOT * sizeof(int));  // 9.4 MB buckets
  float* Map  = (float*)alloc((size_t)NPn * Hh * sizeof(float));
  float* Mpa  = (float*)alloc((size_t)NAn * Hh * sizeof(float));
  float* h1p0 = (float*)alloc((size_t)NPn * Hh * sizeof(float));
  float* h1a0 = (float*)alloc((size_t)NAn * Hh * sizeof(float));
  float* h2p0 = (float*)alloc((size_t)NPn * Hh * sizeof(float));
  float* h2a0 = (float*)alloc((size_t)NAn * Hh * sizeof(float));
  float* P1pp = (float*)alloc((size_t)NPn * 256 * sizeof(float));
  float* P2pp = (float*)alloc((size_t)NPn * 256 * sizeof(float));
  float* P1aa = (float*)alloc((size_t)NAn * 256 * sizeof(float));
  float* P2aa = (float*)alloc((size_t)NAn * 256 * sizeof(float));

  // bucket cnt offsets
  const int CO_PPD = 0, CO_AAD = 4096, CO_PAD = 6144, CO_APD = 8192;

  hipMemsetAsync(cnt, 0, 18432 * sizeof(int), stream);
  scatter_kernel<<<2560, 256, 0, stream>>>(src_pp, dst_pp, src_aa, dst_aa,
                                           src_pa, dst_pa, src_ap, dst_ap,
                                           cnt, entries);

  // ---- K1: GNN1-L0 fused (agg+gemm) + agg-only Map/Mpa ----
  {
    FArgs fa{};
    fa.d[0] = {x_p, nullptr, CO_PPD, 18, nullptr,
               x_p, Wself_p0, Wpp0, nullptr, nullptr, h1p0, 1,
               nullptr, nullptr, nullptr};
    fa.d[1] = {x_a, nullptr, CO_AAD, 16, nullptr,
               x_a, Wself_a0, Waa0, nullptr, nullptr, h1a0, 1,
               nullptr, nullptr, nullptr};
    fa.d[2] = {x_a, nullptr, CO_APD, 0, Map,
               nullptr, nullptr, nullptr, nullptr, nullptr, nullptr, 0,
               nullptr, nullptr, nullptr};
    fa.d[3] = {x_p, nullptr, CO_PAD, 0, Mpa,
               nullptr, nullptr, nullptr, nullptr, nullptr, nullptr, 0,
               nullptr, nullptr, nullptr};
    fa.bstart[0] = 0; fa.bstart[1] = 256; fa.bstart[2] = 384;
    fa.bstart[3] = 640; fa.bstart[4] = 768; fa.nd = 4;
    fused_layer<<<768, 256, 0, stream>>>(fa, cnt, entries);
  }

  // ---- K2: GNN1-L1 fused (agg+gemm) + P projections; h1p1 never materialized ----
  {
    FArgs fa{};
    fa.d[0] = {h1p0, nullptr, CO_PPD, 18, nullptr,
               h1p0, Wself_p1, Wpp1, nullptr, nullptr, nullptr, 1,
               Wep1_pp, P1pp, P2pp};
    fa.d[1] = {h1a0, nullptr, CO_AAD, 16, nullptr,
               h1a0, Wself_a1, Waa1, nullptr, nullptr, nullptr, 1,
               Wep1_aa, P1aa, P2aa};
    fa.bstart[0] = 0; fa.bstart[1] = 256; fa.bstart[2] = 384; fa.nd = 2;
    fused_layer<<<384, 256, 0, stream>>>(fa, cnt, entries);
  }

  // ---- JAX keys: key(42) -> split -> (kpp, kaa) (partitionable fold-in) ----
  uint32_t kpp0, kpp1, kaa0, kaa1;
  { uint32_t a0 = 0, a1 = 0; tf2x32(0u, 42u, a0, a1); kpp0 = a0; kpp1 = a1; }
  { uint32_t a0 = 0, a1 = 1; tf2x32(0u, 42u, a0, a1); kaa0 = a0; kaa1 = a1; }

  // ---- fused edge-pred + sparse coalesce + gumbel top-5 + w write ----
  row_topk<<<NPn + NAn, 256, 0, stream>>>(P1pp, P2pp, bep1_pp, Wep2_pp, bep2_pp,
                                          P1aa, P2aa, bep1_aa, Wep2_aa, bep2_aa,
                                          cnt, entries, w_pp_out, w_aa_out,
                                          kpp0, kpp1, kaa0, kaa1);

  // ---- K3: GNN2-L0 fused (weighted agg + 3-part gemm; Map/Mpa from K1) ----
  {
    FArgs fa{};
    fa.d[0] = {x_p, w_pp_out, CO_PPD, 18, nullptr,
               x_p, Wself_p0, Wpp0, Map, Wap0, h2p0, 1,
               nullptr, nullptr, nullptr};
    fa.d[1] = {x_a, w_aa_out, CO_AAD, 16, nullptr,
               x_a, Wself_a0, Waa0, Mpa, Wpa0, h2a0, 1,
               nullptr, nullptr, nullptr};
    fa.bstart[0] = 0; fa.bstart[1] = 256; fa.bstart[2] = 384; fa.nd = 2;
    fused_layer<<<384, 256, 0, stream>>>(fa, cnt, entries);
  }

  // ---- GNN2 layer 1 only needed at one paper row -> fused with classifier ----
  final_kernel<<<1, 128, 0, stream>>>(h2p0, h2a0, idxPtr, w_pp_out,
                                      cnt, entries,
                                      Wself_p1, Wpp1, Wap1, Wc, bc, out);
}

// Round 10
// 360.227 us; speedup vs baseline: 1.1981x; 1.1981x over previous
//
#include <hip/hip_runtime.h>
#include <stdint.h>

// ---------------------------------------------------------------------------
// MultiGraph hetero-GNN + gumbel-top-k edge pruning, fp32 throughout.
// Round 10: REVERT to r7 (361us, conflicts=0). r8/r9 agg+GEMM fusion falsified:
// shape mismatch (agg wants many small blocks, GEMM wants 64-row tiles); r9's
// staging read pattern caused 4-way bank conflicts (22.9M). r7 = split kernels,
// bucket CSR, sparse topk, batched agg/GEMM — the verified local optimum.
// PRNG: JAX threefry2x32, partitionable path (verified absmax=0.0 r1-r9).
// ---------------------------------------------------------------------------

namespace {

constexpr int NPn = 4096;
constexpr int NAn = 2048;
constexpr int Hh  = 128;
constexpr int EPPc = 131072;
constexpr int EAAc = 65536;
constexpr int KSEL = 5;
constexpr int BSLOT = 128;   // bucket capacity per node (deg<128: Poisson-32, e^-85 tail)

// bucket segments (cnt index = co + node; entries base = (co+node)*128):
// 0: pp-dst (4096)   4096: aa-dst (2048)   6144: pa-dst (2048)
// 8192: ap-dst (4096) 12288: pp-src (4096) 16384: aa-src (2048)
// payloads: pp: (other<<18)|e  aa: (other<<16)|e  pa/ap: src only

__host__ __device__ static inline void tf2x32(uint32_t k0, uint32_t k1,
                                              uint32_t& x0, uint32_t& x1) {
  uint32_t ks2 = k0 ^ k1 ^ 0x1BD11BDAu;
  x0 += k0; x1 += k1;
#define TF_R(r) { x0 += x1; x1 = (x1 << (r)) | (x1 >> (32 - (r))); x1 ^= x0; }
  TF_R(13) TF_R(15) TF_R(26) TF_R(6)
  x0 += k1;  x1 += ks2 + 1u;
  TF_R(17) TF_R(29) TF_R(16) TF_R(24)
  x0 += ks2; x1 += k0 + 2u;
  TF_R(13) TF_R(15) TF_R(26) TF_R(6)
  x0 += k0;  x1 += k1 + 3u;
  TF_R(17) TF_R(29) TF_R(16) TF_R(24)
  x0 += k1;  x1 += ks2 + 4u;
  TF_R(13) TF_R(15) TF_R(26) TF_R(6)
  x0 += ks2; x1 += k0 + 5u;
#undef TF_R
}

// ---------------- bucket scatter (replaces hist+scan+scatter) ----------------
__global__ __launch_bounds__(256) void scatter_kernel(
    const int* src_pp, const int* dst_pp, const int* src_aa, const int* dst_aa,
    const int* src_pa, const int* dst_pa, const int* src_ap, const int* dst_ap,
    int* cnt, int* entries)
{
  int i = blockIdx.x * 256 + threadIdx.x;
  int key, pl;
  if (i < 131072) {                       // pp by dst
    int e = i;
    key = 0 + dst_pp[e]; pl = (src_pp[e] << 18) | e;
  } else if (i < 196608) {                // aa by dst
    int e = i - 131072;
    key = 4096 + dst_aa[e]; pl = (src_aa[e] << 16) | e;
  } else if (i < 327680) {                // pa by dst (payload = src paper)
    int e = i - 196608;
    key = 6144 + dst_pa[e]; pl = src_pa[e];
  } else if (i < 458752) {                // ap by dst (payload = src author)
    int e = i - 327680;
    key = 8192 + dst_ap[e]; pl = src_ap[e];
  } else if (i < 589824) {                // pp by src (payload = (dst<<18)|e)
    int e = i - 458752;
    key = 12288 + src_pp[e]; pl = (dst_pp[e] << 18) | e;
  } else if (i < 655360) {                // aa by src
    int e = i - 589824;
    key = 16384 + src_aa[e]; pl = (dst_aa[e] << 16) | e;
  } else return;
  int pos = atomicAdd(&cnt[key], 1);
  if (pos < BSLOT) entries[key * BSLOT + pos] = pl;
}

// ---------------- batched mean aggregation (bucket CSR) --------------------------------
// 2 nodes per wave: half-wave (32 lanes) per node, lane covers 4 floats (float4).
// Per-node edge loop sequential in slot order (same as r2-r6 order mechanism).
struct AggSeg { const float* h; const float* w; float* M; int cntOff; int shift; };
struct AggArgs { AggSeg s[4]; int start[5]; int nseg; };

__global__ __launch_bounds__(256) void multi_agg(AggArgs a, const int* __restrict__ cnt,
                                                 const int* __restrict__ entries)
{
  int g = blockIdx.x * 8 + (threadIdx.x >> 5);   // 8 half-waves = 8 nodes per block
  int fl = (threadIdx.x & 31) << 2;              // float4 feature offset
  if (g >= a.start[a.nseg]) return;
  int si = 0;
  while (si < a.nseg - 1 && g >= a.start[si + 1]) ++si;
  AggSeg sg = a.s[si];
  int node = g - a.start[si];
  int deg = cnt[sg.cntOff + node];
  const int* ent = entries + (size_t)(sg.cntOff + node) * BSLOT;
  int b = 0, e = deg;
  const float* h = sg.h;
  int sh = sg.shift;
  float ax = 0.f, ay = 0.f, az = 0.f, aw = 0.f;
  if (sg.w) {
    unsigned mask = (1u << sh) - 1u;
    int k = b;
    for (; k + 3 < e; k += 4) {
      unsigned p0 = (unsigned)ent[k], p1 = (unsigned)ent[k + 1];
      unsigned p2 = (unsigned)ent[k + 2], p3 = (unsigned)ent[k + 3];
      float w0 = sg.w[p0 & mask], w1 = sg.w[p1 & mask];
      float w2v = sg.w[p2 & mask], w3 = sg.w[p3 & mask];
      float4 v0, v1, v2, v3;
      if (w0 != 0.f) v0 = *(const float4*)&h[(size_t)(p0 >> sh) * Hh + fl];
      if (w1 != 0.f) v1 = *(const float4*)&h[(size_t)(p1 >> sh) * Hh + fl];
      if (w2v != 0.f) v2 = *(const float4*)&h[(size_t)(p2 >> sh) * Hh + fl];
      if (w3 != 0.f) v3 = *(const float4*)&h[(size_t)(p3 >> sh) * Hh + fl];
      if (w0 != 0.f) { ax += v0.x; ay += v0.y; az += v0.z; aw += v0.w; }
      if (w1 != 0.f) { ax += v1.x; ay += v1.y; az += v1.z; aw += v1.w; }
      if (w2v != 0.f) { ax += v2.x; ay += v2.y; az += v2.z; aw += v2.w; }
      if (w3 != 0.f) { ax += v3.x; ay += v3.y; az += v3.z; aw += v3.w; }
    }
    for (; k < e; ++k) {
      unsigned pl = (unsigned)ent[k];
      float wt = sg.w[pl & mask];
      if (wt != 0.f) {
        float4 v = *(const float4*)&h[(size_t)(pl >> sh) * Hh + fl];
        ax += v.x; ay += v.y; az += v.z; aw += v.w;
      }
    }
  } else {
    int k = b;
    for (; k + 7 < e; k += 8) {
      unsigned p0 = (unsigned)ent[k],     p1 = (unsigned)ent[k + 1];
      unsigned p2 = (unsigned)ent[k + 2], p3 = (unsigned)ent[k + 3];
      unsigned p4 = (unsigned)ent[k + 4], p5 = (unsigned)ent[k + 5];
      unsigned p6 = (unsigned)ent[k + 6], p7 = (unsigned)ent[k + 7];
      float4 v0 = *(const float4*)&h[(size_t)(p0 >> sh) * Hh + fl];
      float4 v1 = *(const float4*)&h[(size_t)(p1 >> sh) * Hh + fl];
      float4 v2 = *(const float4*)&h[(size_t)(p2 >> sh) * Hh + fl];
      float4 v3 = *(const float4*)&h[(size_t)(p3 >> sh) * Hh + fl];
      float4 v4 = *(const float4*)&h[(size_t)(p4 >> sh) * Hh + fl];
      float4 v5 = *(const float4*)&h[(size_t)(p5 >> sh) * Hh + fl];
      float4 v6 = *(const float4*)&h[(size_t)(p6 >> sh) * Hh + fl];
      float4 v7 = *(const float4*)&h[(size_t)(p7 >> sh) * Hh + fl];
      ax += v0.x; ay += v0.y; az += v0.z; aw += v0.w;
      ax += v1.x; ay += v1.y; az += v1.z; aw += v1.w;
      ax += v2.x; ay += v2.y; az += v2.z; aw += v2.w;
      ax += v3.x; ay += v3.y; az += v3.z; aw += v3.w;
      ax += v4.x; ay += v4.y; az += v4.z; aw += v4.w;
      ax += v5.x; ay += v5.y; az += v5.z; aw += v5.w;
      ax += v6.x; ay += v6.y; az += v6.z; aw += v6.w;
      ax += v7.x; ay += v7.y; az += v7.z; aw += v7.w;
    }
    for (; k < e; ++k) {
      unsigned pl = (unsigned)ent[k];
      float4 v = *(const float4*)&h[(size_t)(pl >> sh) * Hh + fl];
      ax += v.x; ay += v.y; az += v.z; aw += v.w;
    }
  }
  float cd = fmaxf((float)deg, 1.0f);
  float4 o; o.x = ax / cd; o.y = ay / cd; o.z = az / cd; o.w = aw / cd;
  *(float4*)&sg.M[(size_t)node * Hh + fl] = o;
}

// ---------------- batched multi-part fp32 GEMM (dbuf; conflict-free layout) ------------
struct GDesc {
  const float* A0; const float* W0; const float* A1; const float* W1;
  const float* A2; const float* W2; float* C; int M; int N; int parts; int relu;
};
struct GArgs { GDesc d[4]; int bstart[5]; int nd; };

__global__ __launch_bounds__(256) void gemm_b(GArgs g)
{
  __shared__ __align__(16) float As[2][32][68];  // [buf][k][m]
  __shared__ __align__(16) float Ws[2][32][68];  // [buf][k][n]
  int blk = blockIdx.x;
  int di = 0;
  while (di < g.nd - 1 && blk >= g.bstart[di + 1]) ++di;
  GDesc D = g.d[di];
  int local = blk - g.bstart[di];
  int nTiles = D.N >> 6;
  int bx = local % nTiles;
  int by = local / nTiles;
  int m0 = by << 6, n0 = bx << 6;
  int N = D.N;
  int tid = threadIdx.x;
  int tr = tid >> 4, tc = tid & 15;
  int r = tid >> 3, f = tid & 7;
  float acc[4][4] = {{0.f}};
  const float* Ap[3] = {D.A0, D.A1, D.A2};
  const float* Wp[3] = {D.W0, D.W1, D.W2};
  int T = D.parts << 2;            // chunks: part-major, k0 = (t&3)*32

  float4 va0, va1, vw0, vw1;
  auto ldchunk = [&](int t) {
    const float* A = Ap[t >> 2]; const float* W = Wp[t >> 2];
    int k0 = (t & 3) << 5;
    va0 = *(const float4*)&A[(size_t)(m0 + r) * 128 + k0 + f * 4];
    va1 = *(const float4*)&A[(size_t)(m0 + r + 32) * 128 + k0 + f * 4];
    vw0 = *(const float4*)&W[(size_t)(k0 + r) * N + n0 + f * 4];
    vw1 = *(const float4*)&W[(size_t)(k0 + r) * N + n0 + f * 4 + 32];
  };
  auto stchunk = [&](int buf) {
    As[buf][f * 4 + 0][r] = va0.x; As[buf][f * 4 + 1][r] = va0.y;
    As[buf][f * 4 + 2][r] = va0.z; As[buf][f * 4 + 3][r] = va0.w;
    As[buf][f * 4 + 0][r + 32] = va1.x; As[buf][f * 4 + 1][r + 32] = va1.y;
    As[buf][f * 4 + 2][r + 32] = va1.z; As[buf][f * 4 + 3][r + 32] = va1.w;
    *(float4*)&Ws[buf][r][f * 4] = vw0;
    *(float4*)&Ws[buf][r][f * 4 + 32] = vw1;
  };

  ldchunk(0);
  stchunk(0);
  __syncthreads();
  for (int t = 0; t < T; ++t) {
    int cur = t & 1;
    bool more = (t + 1 < T);
    if (more) ldchunk(t + 1);      // global loads in flight during compute
#pragma unroll
    for (int k = 0; k < 32; ++k) {
      float4 a = *(const float4*)&As[cur][k][tr * 4];
      float4 b = *(const float4*)&Ws[cur][k][tc * 4];
      acc[0][0] += a.x * b.x; acc[0][1] += a.x * b.y; acc[0][2] += a.x * b.z; acc[0][3] += a.x * b.w;
      acc[1][0] += a.y * b.x; acc[1][1] += a.y * b.y; acc[1][2] += a.y * b.z; acc[1][3] += a.y * b.w;
      acc[2][0] += a.z * b.x; acc[2][1] += a.z * b.y; acc[2][2] += a.z * b.z; acc[2][3] += a.z * b.w;
      acc[3][0] += a.w * b.x; acc[3][1] += a.w * b.y; acc[3][2] += a.w * b.z; acc[3][3] += a.w * b.w;
    }
    if (more) stchunk(cur ^ 1);
    __syncthreads();
  }
#pragma unroll
  for (int i = 0; i < 4; ++i) {
    float4 v;
    v.x = acc[i][0]; v.y = acc[i][1]; v.z = acc[i][2]; v.w = acc[i][3];
    if (D.relu) {
      v.x = fmaxf(v.x, 0.f); v.y = fmaxf(v.y, 0.f);
      v.z = fmaxf(v.z, 0.f); v.w = fmaxf(v.w, 0.f);
    }
    *(float4*)&D.C[(size_t)(m0 + tr * 4 + i) * N + n0 + tc * 4] = v;
  }
}

// ---------------- fused edge-MLP + sparse coalesce + masked gumbel top-5 + w write ------
__global__ __launch_bounds__(256) void row_topk(
    const float* __restrict__ P1pp, const float* __restrict__ P2pp,
    const float* __restrict__ b1pp, const float* __restrict__ W2pp,
    const float* __restrict__ b2pp,
    const float* __restrict__ P1aa, const float* __restrict__ P2aa,
    const float* __restrict__ b1aa, const float* __restrict__ W2aa,
    const float* __restrict__ b2aa,
    const int* __restrict__ cnt, const int* __restrict__ entries,
    float* __restrict__ w_pp, float* __restrict__ w_aa,
    uint32_t kpp0, uint32_t kpp1, uint32_t kaa0, uint32_t kaa1)
{
  __shared__ float P1s[256], b1s[256], w2s[256];
  __shared__ int   dS[128];
  __shared__ float pS[128];
  __shared__ int   sel5[KSEL];
  int blk = blockIdx.x, tid = threadIdx.x;
  int lane = tid & 63, wv = tid >> 6;
  int row, Ncols, shift, co; unsigned mask;
  const float* P1; const float* P2; const float* b1; const float* W2; const float* b2;
  float* wout; uint32_t k0, k1;
  if (blk < NPn) {
    row = blk; Ncols = NPn; shift = 18; mask = 0x3FFFFu; co = 12288;
    P1 = P1pp; P2 = P2pp; b1 = b1pp; W2 = W2pp; b2 = b2pp;
    wout = w_pp; k0 = kpp0; k1 = kpp1;
  } else {
    row = blk - NPn; Ncols = NAn; shift = 16; mask = 0xFFFFu; co = 16384;
    P1 = P1aa; P2 = P2aa; b1 = b1aa; W2 = W2aa; b2 = b2aa;
    wout = w_aa; k0 = kaa0; k1 = kaa1;
  }
  const int* ent = entries + (size_t)(co + row) * BSLOT;
  int deg = cnt[co + row];
  P1s[tid] = P1[(size_t)row * 256 + tid];
  b1s[tid] = b1[tid];
  w2s[tid] = W2[tid * 2];
  __syncthreads();
  float bias2 = b2[0];
  // --- edge phase: 4 edges per wave, bit-exact arithmetic; lane0 -> LDS slots ---
  int j = lane << 2;
  for (int k = wv * 4; k < deg; k += 16) {
    int n = deg - k; if (n > 4) n = 4;
    unsigned pl0 = (unsigned)ent[k];
    unsigned pl1 = (n > 1) ? (unsigned)ent[k + 1] : pl0;
    unsigned pl2 = (n > 2) ? (unsigned)ent[k + 2] : pl0;
    unsigned pl3 = (n > 3) ? (unsigned)ent[k + 3] : pl0;
    int d0 = (int)(pl0 >> shift), d1 = (int)(pl1 >> shift);
    int d2 = (int)(pl2 >> shift), d3 = (int)(pl3 >> shift);
    float4 q0 = *(const float4*)&P2[(size_t)d0 * 256 + j];
    float4 q1 = *(const float4*)&P2[(size_t)d1 * 256 + j];
    float4 q2 = *(const float4*)&P2[(size_t)d2 * 256 + j];
    float4 q3 = *(const float4*)&P2[(size_t)d3 * 256 + j];
    float pa = P1s[j + 0], pb = P1s[j + 1], pc = P1s[j + 2], pd = P1s[j + 3];
    float ba = b1s[j + 0], bb = b1s[j + 1], bc_ = b1s[j + 2], bd = b1s[j + 3];
    float wa = w2s[j + 0], wb = w2s[j + 1], wc = w2s[j + 2], wd = w2s[j + 3];
    float s0 = fmaxf(pa + q0.x + ba, 0.f) * wa + fmaxf(pb + q0.y + bb, 0.f) * wb +
               fmaxf(pc + q0.z + bc_, 0.f) * wc + fmaxf(pd + q0.w + bd, 0.f) * wd;
    float s1 = fmaxf(pa + q1.x + ba, 0.f) * wa + fmaxf(pb + q1.y + bb, 0.f) * wb +
               fmaxf(pc + q1.z + bc_, 0.f) * wc + fmaxf(pd + q1.w + bd, 0.f) * wd;
    float s2 = fmaxf(pa + q2.x + ba, 0.f) * wa + fmaxf(pb + q2.y + bb, 0.f) * wb +
               fmaxf(pc + q2.z + bc_, 0.f) * wc + fmaxf(pd + q2.w + bd, 0.f) * wd;
    float s3 = fmaxf(pa + q3.x + ba, 0.f) * wa + fmaxf(pb + q3.y + bb, 0.f) * wb +
               fmaxf(pc + q3.z + bc_, 0.f) * wc + fmaxf(pd + q3.w + bd, 0.f) * wd;
    for (int off = 32; off; off >>= 1) {
      s0 += __shfl_down(s0, off);
      s1 += __shfl_down(s1, off);
      s2 += __shfl_down(s2, off);
      s3 += __shfl_down(s3, off);
    }
    if (lane == 0) {
      dS[k] = d0; pS[k] = s0 + bias2;
      if (n > 1) { dS[k + 1] = d1; pS[k + 1] = s1 + bias2; }
      if (n > 2) { dS[k + 2] = d2; pS[k + 2] = s2 + bias2; }
      if (n > 3) { dS[k + 3] = d3; pS[k + 3] = s3 + bias2; }
    }
  }
  __syncthreads();
  if (deg > 0 && wv == 0) {
    // --- dedupe (ascending-slot sums) + gumbel + top-5, all in wave 0 ---
    int   e0 = (lane < deg) ? dS[lane] : -1;
    float q0v = (lane < deg) ? pS[lane] : 0.f;
    bool  two = (deg > 64);
    int   e1 = -1; float q1v = 0.f;
    if (two && 64 + lane < deg) { e1 = dS[64 + lane]; q1v = pS[64 + lane]; }
    float a0 = 0.f, a1 = 0.f;
    bool lead0 = (e0 >= 0), lead1 = (e1 >= 0);
    for (int j2 = 0; j2 < deg; ++j2) {
      int bj; float bp;
      if (j2 < 64) { bj = __shfl(e0, j2); bp = __shfl(q0v, j2); }
      else         { bj = __shfl(e1, j2 - 64); bp = __shfl(q1v, j2 - 64); }
      if (e0 >= 0 && bj == e0) { a0 += bp; if (j2 < lane) lead0 = false; }
      if (e1 >= 0 && bj == e1) { a1 += bp; if (j2 < 64 + lane) lead1 = false; }
    }
    uint32_t rowbase = (uint32_t)row * (uint32_t)Ncols;
    float y0 = -1e9f, y1 = -1e9f;
    bool c0 = lead0 && (a0 > 0.f);
    if (c0) {
      uint32_t x0 = 0u, x1 = rowbase + (uint32_t)e0;
      tf2x32(k0, k1, x0, x1);
      uint32_t bits = x0 ^ x1;
      float fv = __uint_as_float((bits >> 9) | 0x3f800000u) - 1.0f;
      float u = fmaxf(1e-10f, fv + 1e-10f);
      y0 = a0 + (-logf(-logf(u)));
    }
    bool c1 = lead1 && (a1 > 0.f);
    if (c1) {
      uint32_t x0 = 0u, x1 = rowbase + (uint32_t)e1;
      tf2x32(k0, k1, x0, x1);
      uint32_t bits = x0 ^ x1;
      float fv = __uint_as_float((bits >> 9) | 0x3f800000u) - 1.0f;
      float u = fmaxf(1e-10f, fv + 1e-10f);
      y1 = a1 + (-logf(-logf(u)));
    }
    int cnt2 = __popcll(__ballot(c0)) + __popcll(__ballot(c1));
    int nsel = cnt2 < KSEL ? cnt2 : KSEL;
    for (int it = 0; it < nsel; ++it) {
      float best; int bc;
      if (y1 > y0 || (y1 == y0 && (unsigned)e1 < (unsigned)e0)) { best = y1; bc = e1; }
      else { best = y0; bc = e0; }
      for (int m = 32; m; m >>= 1) {
        float ov = __shfl_xor(best, m); int oc = __shfl_xor(bc, m);
        if (ov > best || (ov == best && (unsigned)oc < (unsigned)bc)) { best = ov; bc = oc; }
      }
      if (lane == 0) sel5[it] = bc;
      if (e0 == bc) y0 = -3.0e38f;
      if (e1 == bc) y1 = -3.0e38f;
    }
    if (nsel < KSEL && lane == 0) {
      // fill remaining with smallest column indices not yet selected
      int c = 0;
      for (int it = nsel; it < KSEL; ++it) {
        for (;;) {
          bool used = false;
          for (int q = 0; q < it; ++q) used |= (sel5[q] == c);
          if (!used) break;
          ++c;
        }
        sel5[it] = c++;
      }
    }
  }
  __syncthreads();
  // --- write hard 0/1 weights onto this row's edges ---
  for (int k = tid; k < deg; k += 256) {
    unsigned pl = (unsigned)ent[k];
    int d = (int)(pl >> shift);
    int e = (int)(pl & mask);
    float v = 0.f;
#pragma unroll
    for (int q = 0; q < KSEL; ++q) v = (sel5[q] == d) ? 1.f : v;
    wout[e] = v;
  }
}

// ---------------- fused GNN2-layer1 (single row) + classifier (bucket CSR) --------------
__global__ __launch_bounds__(128) void final_kernel(
    const float* __restrict__ hp, const float* __restrict__ ha,
    const int* __restrict__ idxPtr, const float* __restrict__ wpp,
    const int* __restrict__ cnt, const int* __restrict__ entries,
    const float* __restrict__ Wself, const float* __restrict__ Wpp,
    const float* __restrict__ Wap,
    const float* __restrict__ Wc, const float* __restrict__ bc,
    float* __restrict__ out)
{
  __shared__ float selfr[128], mpp[128], mapr[128], t[128];
  int tid = threadIdx.x;
  int idx = idxPtr[0];
  selfr[tid] = hp[(size_t)idx * 128 + tid];
  {
    int deg = cnt[idx];                                   // pp-dst bucket
    const int* ent = entries + (size_t)idx * BSLOT;
    float acc = 0.f;
    for (int k = 0; k < deg; ++k) {
      unsigned pl = (unsigned)ent[k];
      int s = (int)(pl >> 18);
      int e = (int)(pl & 0x3FFFFu);
      acc += wpp[e] * hp[(size_t)s * 128 + tid];
    }
    mpp[tid] = acc / fmaxf((float)deg, 1.0f);
  }
  {
    int deg = cnt[8192 + idx];                            // ap-dst bucket
    const int* ent = entries + (size_t)(8192 + idx) * BSLOT;
    float acc = 0.f;
    for (int k = 0; k < deg; ++k) {
      int s = ent[k];
      acc += ha[(size_t)s * 128 + tid];
    }
    mapr[tid] = acc / fmaxf((float)deg, 1.0f);
  }
  __syncthreads();
  float s = 0.f;
  for (int m = 0; m < 128; ++m) {
    s += selfr[m] * Wself[m * 128 + tid] + mpp[m] * Wpp[m * 128 + tid] +
         mapr[m] * Wap[m * 128 + tid];
  }
  t[tid] = fmaxf(s, 0.f);
  __syncthreads();
  if (tid < 5) {
    float y = bc[tid];
    for (int k = 0; k < 128; ++k) y += t[k] * Wc[k * 5 + tid];
    out[tid] = y;
  }
}

}  // namespace

extern "C" void kernel_launch(void* const* d_in, const int* in_sizes, int n_in,
                              void* d_out, int out_size, void* d_ws, size_t ws_size,
                              hipStream_t stream)
{
  (void)in_sizes; (void)n_in; (void)out_size; (void)ws_size;
  const float* x_p = (const float*)d_in[0];
  const float* x_a = (const float*)d_in[1];
  const int* ei_pp = (const int*)d_in[2];
  const int* ei_aa = (const int*)d_in[3];
  const int* ei_pa = (const int*)d_in[4];
  const int* ei_ap = (const int*)d_in[5];
  const int* idxPtr = (const int*)d_in[8];
  const float* Wself_p0 = (const float*)d_in[9];
  const float* Wself_p1 = (const float*)d_in[10];
  const float* Wself_a0 = (const float*)d_in[11];
  const float* Wself_a1 = (const float*)d_in[12];
  const float* Wpp0 = (const float*)d_in[13]; const float* Wpp1 = (const float*)d_in[14];
  const float* Waa0 = (const float*)d_in[15]; const float* Waa1 = (const float*)d_in[16];
  const float* Wpa0 = (const float*)d_in[17]; /* Wpa1 unused: author L1 dropped */
  const float* Wap0 = (const float*)d_in[19]; const float* Wap1 = (const float*)d_in[20];
  const float* Wep1_pp = (const float*)d_in[21]; const float* bep1_pp = (const float*)d_in[22];
  const float* Wep2_pp = (const float*)d_in[23]; const float* bep2_pp = (const float*)d_in[24];
  const float* Wep1_aa = (const float*)d_in[25]; const float* bep1_aa = (const float*)d_in[26];
  const float* Wep2_aa = (const float*)d_in[27]; const float* bep2_aa = (const float*)d_in[28];
  const float* Wc = (const float*)d_in[29]; const float* bc = (const float*)d_in[30];

  float* out = (float*)d_out;
  float* w_pp_out = out + 5;
  float* w_aa_out = out + 5 + EPPc;

  const int* src_pp = ei_pp;  const int* dst_pp = ei_pp + EPPc;
  const int* src_aa = ei_aa;  const int* dst_aa = ei_aa + EAAc;
  const int* src_pa = ei_pa;  const int* dst_pa = ei_pa + 131072;
  const int* src_ap = ei_ap;  const int* dst_ap = ei_ap + 131072;

  // ---- workspace layout (bump allocator; cnt first: it gets memset) ----
  char* p = (char*)d_ws;
  auto alloc = [&](size_t bytes) -> void* {
    void* r = (void*)p;
    p += (bytes + 255) & ~(size_t)255;
    return r;
  };
  int* cnt     = (int*)alloc(18432 * sizeof(int));
  int* entries = (int*)alloc((size_t)18432 * BSLOT * sizeof(int));  // 9.4 MB buckets
  float* Mpp  = (float*)alloc((size_t)NPn * Hh * sizeof(float));
  float* Maa  = (float*)alloc((size_t)NAn * Hh * sizeof(float));
  float* Mpa  = (float*)alloc((size_t)NAn * Hh * sizeof(float));
  float* Map  = (float*)alloc((size_t)NPn * Hh * sizeof(float));
  float* h1p0 = (float*)alloc((size_t)NPn * Hh * sizeof(float));
  float* h1a0 = (float*)alloc((size_t)NAn * Hh * sizeof(float));
  float* h1p1 = (float*)alloc((size_t)NPn * Hh * sizeof(float));
  float* h1a1 = (float*)alloc((size_t)NAn * Hh * sizeof(float));
  float* h2p0 = (float*)alloc((size_t)NPn * Hh * sizeof(float));
  float* h2a0 = (float*)alloc((size_t)NAn * Hh * sizeof(float));
  float* P1pp = (float*)alloc((size_t)NPn * 256 * sizeof(float));
  float* P2pp = (float*)alloc((size_t)NPn * 256 * sizeof(float));
  float* P1aa = (float*)alloc((size_t)NAn * 256 * sizeof(float));
  float* P2aa = (float*)alloc((size_t)NAn * 256 * sizeof(float));

  // bucket cnt offsets
  const int CO_PPD = 0, CO_AAD = 4096, CO_PAD = 6144, CO_APD = 8192;

  hipMemsetAsync(cnt, 0, 18432 * sizeof(int), stream);
  scatter_kernel<<<2560, 256, 0, stream>>>(src_pp, dst_pp, src_aa, dst_aa,
                                           src_pa, dst_pa, src_ap, dst_ap,
                                           cnt, entries);

  // ---- agg1: GNN1-L0 means (pp,aa) + w-independent GNN2 means (ap,pa) ----
  {
    AggArgs a{};
    a.s[0] = {x_p, nullptr, Mpp, CO_PPD, 18};
    a.s[1] = {x_a, nullptr, Maa, CO_AAD, 16};
    a.s[2] = {x_a, nullptr, Map, CO_APD, 0};
    a.s[3] = {x_p, nullptr, Mpa, CO_PAD, 0};
    a.start[0] = 0; a.start[1] = NPn; a.start[2] = NPn + NAn;
    a.start[3] = 2 * NPn + NAn; a.start[4] = 2 * NPn + 2 * NAn; a.nseg = 4;
    multi_agg<<<(2 * NPn + 2 * NAn) / 8, 256, 0, stream>>>(a, cnt, entries);
  }
  {
    GArgs g{};
    g.d[0] = {x_p, Wself_p0, Mpp, Wpp0, nullptr, nullptr, h1p0, NPn, 128, 2, 1};
    g.d[1] = {x_a, Wself_a0, Maa, Waa0, nullptr, nullptr, h1a0, NAn, 128, 2, 1};
    g.bstart[0] = 0; g.bstart[1] = 128; g.bstart[2] = 192; g.nd = 2;
    gemm_b<<<192, 256, 0, stream>>>(g);
  }
  {
    AggArgs a{};
    a.s[0] = {h1p0, nullptr, Mpp, CO_PPD, 18};
    a.s[1] = {h1a0, nullptr, Maa, CO_AAD, 16};
    a.start[0] = 0; a.start[1] = NPn; a.start[2] = NPn + NAn; a.nseg = 2;
    multi_agg<<<(NPn + NAn) / 8, 256, 0, stream>>>(a, cnt, entries);
  }
  {
    GArgs g{};
    g.d[0] = {h1p0, Wself_p1, Mpp, Wpp1, nullptr, nullptr, h1p1, NPn, 128, 2, 1};
    g.d[1] = {h1a0, Wself_a1, Maa, Waa1, nullptr, nullptr, h1a1, NAn, 128, 2, 1};
    g.bstart[0] = 0; g.bstart[1] = 128; g.bstart[2] = 192; g.nd = 2;
    gemm_b<<<192, 256, 0, stream>>>(g);
  }

  // ---- edge MLP node projections: concat(h_s,h_d)@Wep1 == P1[s] + P2[d] ----
  {
    GArgs g{};
    g.d[0] = {h1p1, Wep1_pp,             nullptr, nullptr, nullptr, nullptr, P1pp, NPn, 256, 1, 0};
    g.d[1] = {h1p1, Wep1_pp + 128 * 256, nullptr, nullptr, nullptr, nullptr, P2pp, NPn, 256, 1, 0};
    g.d[2] = {h1a1, Wep1_aa,             nullptr, nullptr, nullptr, nullptr, P1aa, NAn, 256, 1, 0};
    g.d[3] = {h1a1, Wep1_aa + 128 * 256, nullptr, nullptr, nullptr, nullptr, P2aa, NAn, 256, 1, 0};
    g.bstart[0] = 0; g.bstart[1] = 256; g.bstart[2] = 512; g.bstart[3] = 640;
    g.bstart[4] = 768; g.nd = 4;
    gemm_b<<<768, 256, 0, stream>>>(g);
  }

  // ---- JAX keys: key(42) -> split -> (kpp, kaa) (partitionable fold-in) ----
  uint32_t kpp0, kpp1, kaa0, kaa1;
  { uint32_t a0 = 0, a1 = 0; tf2x32(0u, 42u, a0, a1); kpp0 = a0; kpp1 = a1; }
  { uint32_t a0 = 0, a1 = 1; tf2x32(0u, 42u, a0, a1); kaa0 = a0; kaa1 = a1; }

  // ---- fused edge-pred + sparse coalesce + gumbel top-5 + w write ----
  row_topk<<<NPn + NAn, 256, 0, stream>>>(P1pp, P2pp, bep1_pp, Wep2_pp, bep2_pp,
                                          P1aa, P2aa, bep1_aa, Wep2_aa, bep2_aa,
                                          cnt, entries, w_pp_out, w_aa_out,
                                          kpp0, kpp1, kaa0, kaa1);

  // ---- agg3: weighted pp/aa means only (Map/Mpa already done in agg1) ----
  {
    AggArgs a{};
    a.s[0] = {x_p, w_pp_out, Mpp, CO_PPD, 18};
    a.s[1] = {x_a, w_aa_out, Maa, CO_AAD, 16};
    a.start[0] = 0; a.start[1] = NPn; a.start[2] = NPn + NAn; a.nseg = 2;
    multi_agg<<<(NPn + NAn) / 8, 256, 0, stream>>>(a, cnt, entries);
  }
  {
    GArgs g{};
    g.d[0] = {x_p, Wself_p0, Mpp, Wpp0, Map, Wap0, h2p0, NPn, 128, 3, 1};
    g.d[1] = {x_a, Wself_a0, Maa, Waa0, Mpa, Wpa0, h2a0, NAn, 128, 3, 1};
    g.bstart[0] = 0; g.bstart[1] = 128; g.bstart[2] = 192; g.nd = 2;
    gemm_b<<<192, 256, 0, stream>>>(g);
  }

  // ---- GNN2 layer 1 only needed at one paper row -> fused with classifier ----
  final_kernel<<<1, 128, 0, stream>>>(h2p0, h2a0, idxPtr, w_pp_out,
                                      cnt, entries,
                                      Wself_p1, Wpp1, Wap1, Wc, bc, out);
}